// Round 5
// baseline (312.512 us; speedup 1.0000x reference)
//
#include <hip/hip_runtime.h>
#include <hip/hip_bf16.h>

#define D_MODEL 1024
#define NUM_HEADS 16
#define HEAD_DIM 64
#define SEQ 2048
#define BATCH 2
#define ROWS (BATCH * SEQ)  // 4096

typedef unsigned short u16;
typedef __bf16 bf16x8 __attribute__((ext_vector_type(8)));
typedef float f32x4 __attribute__((ext_vector_type(4)));

__device__ inline u16 f2bfu(float f) {
  // RNE float->bf16
  unsigned u = __float_as_uint(f);
  unsigned r = (u + 0x7fffu + ((u >> 16) & 1u)) >> 16;
  return (u16)r;
}

__device__ inline f32x4 mfma16(bf16x8 a, bf16x8 b, f32x4 c) {
  return __builtin_amdgcn_mfma_f32_16x16x32_bf16(a, b, c, 0, 0, 0);
}

__device__ inline bf16x8 load_frag(const u16* p) {
  union { uint4 v; bf16x8 f; } u;
  u.v = *(const uint4*)p;
  return u.f;
}

// async global->LDS, 16B per lane; LDS dest = wave-uniform base + lane*16
__device__ inline void gload_lds16(const u16* g, u16* l) {
  __builtin_amdgcn_global_load_lds((const __attribute__((address_space(1))) void*)g,
                                   (__attribute__((address_space(3))) void*)l, 16, 0, 0);
}

// ---------------- converters ----------------

__global__ __launch_bounds__(256) void cvt_x_kernel(const float* __restrict__ x,
                                                    u16* __restrict__ y) {
  int i = blockIdx.x * 256 + threadIdx.x;  // each handles 4 floats
  float4 v = ((const float4*)x)[i];
  union { u16 s[4]; uint2 v2; } o;
  o.s[0] = f2bfu(v.x); o.s[1] = f2bfu(v.y);
  o.s[2] = f2bfu(v.z); o.s[3] = f2bfu(v.w);
  ((uint2*)y)[i] = o.v2;
}

// W [K][N] fp32 -> Wt [N][K] bf16
__global__ __launch_bounds__(256) void transpose_cvt(const float* __restrict__ W,
                                                     u16* __restrict__ Wt,
                                                     int K, int N) {
  __shared__ float t[32][33];
  int k0 = blockIdx.x * 32, n0 = blockIdx.y * 32;
  int c = threadIdx.x & 31, r8 = threadIdx.x >> 5;
#pragma unroll
  for (int i = 0; i < 4; i++) {
    int r = r8 + i * 8;
    t[r][c] = W[(size_t)(k0 + r) * N + n0 + c];
  }
  __syncthreads();
#pragma unroll
  for (int i = 0; i < 4; i++) {
    int r = r8 + i * 8;
    Wt[(size_t)(n0 + r) * K + k0 + c] = f2bfu(t[c][r]);
  }
}

// ---------------- GEMM 1: qkv = x @ W_qkv + b -> Qb/Kb [bh][s][64], Vt [bh][d][s] ----------------
// 128x128 tile, BK=64, global_load_lds width=16, fragment-ordered LDS.
// LDS layout: 16-row block = 16 rows x 64 k = 1024 u16 (block stride 1024),
// granule kg (8 k) at kg*128, row-in-block at ln*8.

__global__ __launch_bounds__(256) void gemm_qkv(const u16* __restrict__ A,   // xb [4096][1024]
                                                const u16* __restrict__ Bt,  // WqkvT [3072][1024]
                                                const float* __restrict__ bias,
                                                u16* __restrict__ Qb, u16* __restrict__ Kb,
                                                u16* __restrict__ Vt) {
  __shared__ u16 lA[128 * 64];
  __shared__ u16 lB[128 * 64];
  const int tid = threadIdx.x;
  const int wave = tid >> 6, lane = tid & 63, ln = lane & 15, quad = lane >> 4;
  const int n0 = blockIdx.x * 128, m0 = blockIdx.y * 128;
  const int wm = (wave & 1) * 64, wn = (wave >> 1) * 64;
  f32x4 acc[4][4] = {};

  for (int kt = 0; kt < 16; ++kt) {
    const int k0 = kt * 64;
    __syncthreads();
#pragma unroll
    for (int i = 0; i < 4; ++i) {
      int c = wave * 4 + i;  // 16 chunks of 1KB each for A and B
      int rb = c >> 1, kgh = c & 1;
      gload_lds16(A + (size_t)(m0 + rb * 16 + ln) * 1024 + k0 + (kgh * 4 + quad) * 8,
                  lA + rb * 1024 + kgh * 512);
      gload_lds16(Bt + (size_t)(n0 + rb * 16 + ln) * 1024 + k0 + (kgh * 4 + quad) * 8,
                  lB + rb * 1024 + kgh * 512);
    }
    __syncthreads();
#pragma unroll
    for (int ks = 0; ks < 2; ++ks) {
      bf16x8 a[4], b[4];
#pragma unroll
      for (int i = 0; i < 4; ++i) {
        a[i] = load_frag(lA + (wm / 16 + i) * 1024 + (ks * 4 + quad) * 128 + ln * 8);
        b[i] = load_frag(lB + (wn / 16 + i) * 1024 + (ks * 4 + quad) * 128 + ln * 8);
      }
#pragma unroll
      for (int mt = 0; mt < 4; ++mt)
#pragma unroll
        for (int nt = 0; nt < 4; ++nt) acc[mt][nt] = mfma16(a[mt], b[nt], acc[mt][nt]);
    }
  }
#pragma unroll
  for (int mt = 0; mt < 4; ++mt) {
    int row = m0 + wm + mt * 16 + quad * 4;
    int bb = row >> 11, s0 = row & 2047;
#pragma unroll
    for (int nt = 0; nt < 4; ++nt) {
      int col = n0 + wn + nt * 16 + ln;
      float bv = bias[col];
      int h = col / 192, rem = col - h * 192, t3 = rem >> 6, d = rem & 63;
      int bh = bb * NUM_HEADS + h;
      if (t3 == 2) {  // V -> transposed layout [bh][d][s], 4 consecutive s packed
        union { u16 s[4]; uint2 v; } pk;
#pragma unroll
        for (int r = 0; r < 4; ++r) pk.s[r] = f2bfu(acc[mt][nt][r] + bv);
        *(uint2*)(Vt + ((size_t)bh * 64 + d) * SEQ + s0) = pk.v;
      } else {
        u16* dst = (t3 == 0) ? Qb : Kb;
#pragma unroll
        for (int r = 0; r < 4; ++r)
          dst[((size_t)bh * SEQ + s0 + r) * 64 + d] = f2bfu(acc[mt][nt][r] + bv);
      }
    }
  }
}

// ---------------- flash attention, S^T formulation ----------------
// 2 waves/block, 32 q-rows/block; wave w handles K-tiles {w, w+2, ...} (split-K),
// flash-merge at the end via LDS. No barriers in the main loop.
// S^T = K·Q^T  (A-frag = K rows from global, B-frag = Q rows from global)
// O^T = V^T·P^T (A-frag = Vt rows from global, B-frag = P via per-wave swizzled LDS)

__global__ __launch_bounds__(128) void attn_kernel(const u16* __restrict__ Qb,
                                                   const u16* __restrict__ Kb,
                                                   const u16* __restrict__ Vt,
                                                   u16* __restrict__ Ob) {
  __shared__ u16 lP[2][2048];          // per-wave P swizzle buffers (also epilogue transpose)
  __shared__ float fm[32], fl[32];     // wave1 -> wave0 merge state
  __shared__ float fo[64][33];         // wave1 O^T [d][q] (+1 pad)
  const int tid = threadIdx.x;
  const int wave = tid >> 6, lane = tid & 63;
  const int ln = lane & 15, quad = lane >> 4;
  const int qt = gridDim.x - 1 - blockIdx.x;  // heavy blocks first
  const int q0 = qt * 32;
  const int bh = blockIdx.y;
  const u16* Qg = Qb + (size_t)bh * SEQ * 64;
  const u16* Kg = Kb + (size_t)bh * SEQ * 64;
  const u16* Vg = Vt + (size_t)bh * 64 * SEQ;

  // Q B-frags, loaded once: qf[nq][ks] = Q[q0+nq*16+ln][ks*32+quad*8 ..+8]
  bf16x8 qf[2][2];
#pragma unroll
  for (int nq = 0; nq < 2; ++nq)
#pragma unroll
    for (int ks = 0; ks < 2; ++ks)
      qf[nq][ks] = load_frag(Qg + (size_t)(q0 + nq * 16 + ln) * 64 + ks * 32 + quad * 8);

  f32x4 o[4][2] = {};               // O^T: row d=dt*16+quad*4+r, col q=nq*16+ln
  float m_r[2] = {-1e30f, -1e30f};  // per-lane: q = q0+nq*16+ln (exp2 domain)
  float l_r[2] = {0.f, 0.f};
  const int kt_max = (q0 + 31) >> 6;
  u16* lPw = lP[wave];

  for (int kt = wave; kt <= kt_max; kt += 2) {
    // S^T tile: 64 keys x 32 q
    f32x4 sc[4][2] = {};
#pragma unroll
    for (int mt = 0; mt < 4; ++mt) {
      const u16* kr = Kg + (size_t)(kt * 64 + mt * 16 + ln) * 64;
      bf16x8 kf0 = load_frag(kr + quad * 8);
      bf16x8 kf1 = load_frag(kr + 32 + quad * 8);
#pragma unroll
      for (int nq = 0; nq < 2; ++nq) {
        sc[mt][nq] = mfma16(kf0, qf[nq][0], sc[mt][nq]);
        sc[mt][nq] = mfma16(kf1, qf[nq][1], sc[mt][nq]);
      }
    }
    const float SC = 0.18033688011112042f;  // log2(e) / sqrt(64)  (exp2 domain)
    const bool diag = (kt == kt_max);
#pragma unroll
    for (int nq = 0; nq < 2; ++nq) {
      const int qq = q0 + nq * 16 + ln;
      // scale + causal mask (only diagonal tile can mask)
#pragma unroll
      for (int mt = 0; mt < 4; ++mt) {
        int key0 = kt * 64 + mt * 16 + quad * 4;
#pragma unroll
        for (int r = 0; r < 4; ++r) {
          float v = sc[mt][nq][r] * SC;
          if (diag && (key0 + r > qq)) v = -1e30f;
          sc[mt][nq][r] = v;
        }
      }
      // online softmax: 16 in-lane values + butterfly over quads (lanes ^16, ^32)
      float mloc = sc[0][nq][0];
#pragma unroll
      for (int mt = 0; mt < 4; ++mt)
#pragma unroll
        for (int r = 0; r < 4; ++r) mloc = fmaxf(mloc, sc[mt][nq][r]);
      mloc = fmaxf(mloc, __shfl_xor(mloc, 16));
      mloc = fmaxf(mloc, __shfl_xor(mloc, 32));
      float mnew = fmaxf(m_r[nq], mloc);
      float alpha = __builtin_amdgcn_exp2f(m_r[nq] - mnew);
      float sum = 0.f;
#pragma unroll
      for (int mt = 0; mt < 4; ++mt)
#pragma unroll
        for (int r = 0; r < 4; ++r) {
          float p = __builtin_amdgcn_exp2f(sc[mt][nq][r] - mnew);
          sc[mt][nq][r] = p;
          sum += p;
        }
      sum += __shfl_xor(sum, 16);
      sum += __shfl_xor(sum, 32);
      l_r[nq] = l_r[nq] * alpha + sum;
      m_r[nq] = mnew;
#pragma unroll
      for (int dt = 0; dt < 4; ++dt) o[dt][nq] *= alpha;
    }
    // P -> per-wave LDS, [q][k] with k-granule XOR swizzle (bank-spread), packed b64 writes
#pragma unroll
    for (int nq = 0; nq < 2; ++nq)
#pragma unroll
      for (int mt = 0; mt < 4; ++mt) {
        union { u16 s[4]; uint2 v; } pk;
#pragma unroll
        for (int r = 0; r < 4; ++r) pk.s[r] = f2bfu(sc[mt][nq][r]);
        int addr = (nq * 16 + ln) * 64 + (((mt * 2 + (quad >> 1)) ^ (ln & 7)) * 8) + (quad & 1) * 4;
        *(uint2*)(lPw + addr) = pk.v;
      }
    bf16x8 pf[2][2];
#pragma unroll
    for (int ks = 0; ks < 2; ++ks)
#pragma unroll
      for (int nq = 0; nq < 2; ++nq)
        pf[ks][nq] = load_frag(lPw + (nq * 16 + ln) * 64 + (((ks * 4 + quad) ^ (ln & 7)) * 8));
    // O^T += V^T · P^T
#pragma unroll
    for (int dt = 0; dt < 4; ++dt) {
#pragma unroll
      for (int ks = 0; ks < 2; ++ks) {
        bf16x8 av = load_frag(Vg + (size_t)(dt * 16 + ln) * SEQ + kt * 64 + ks * 32 + quad * 8);
#pragma unroll
        for (int nq = 0; nq < 2; ++nq) o[dt][nq] = mfma16(av, pf[ks][nq], o[dt][nq]);
      }
    }
  }

  // ---- flash merge: wave1 publishes state, wave0 combines + stores ----
  if (wave == 1) {
#pragma unroll
    for (int nq = 0; nq < 2; ++nq) {
      int q = nq * 16 + ln;
      if (quad == 0) { fm[q] = m_r[nq]; fl[q] = l_r[nq]; }
#pragma unroll
      for (int dt = 0; dt < 4; ++dt)
#pragma unroll
        for (int r = 0; r < 4; ++r) fo[dt * 16 + quad * 4 + r][q] = o[dt][nq][r];
    }
  }
  __syncthreads();
  if (wave == 0) {
    u16* lbufE = (u16*)lP;  // free after loop; 32*72 u16 fits in 2*2048
#pragma unroll
    for (int nq = 0; nq < 2; ++nq) {
      int q = nq * 16 + ln;
      float m1 = fm[q], l1 = fl[q];
      float mnew = fmaxf(m_r[nq], m1);
      float a0 = __builtin_amdgcn_exp2f(m_r[nq] - mnew);
      float a1 = __builtin_amdgcn_exp2f(m1 - mnew);
      float inv = 1.f / (l_r[nq] * a0 + l1 * a1);
      a0 *= inv; a1 *= inv;
#pragma unroll
      for (int dt = 0; dt < 4; ++dt) {
        union { u16 s[4]; uint2 v; } pk;
#pragma unroll
        for (int r = 0; r < 4; ++r)
          pk.s[r] = f2bfu(o[dt][nq][r] * a0 + fo[dt * 16 + quad * 4 + r][q] * a1);
        *(uint2*)(lbufE + q * 72 + dt * 16 + quad * 4) = pk.v;
      }
    }
    const int b = bh >> 4, h = bh & 15;
#pragma unroll
    for (int i = 0; i < 4; ++i) {
      int c = lane + i * 64;
      int qq = c >> 3, dg = c & 7;
      uint4 val = *(const uint4*)(lbufE + qq * 72 + dg * 8);
      *(uint4*)(Ob + ((size_t)b * SEQ + q0 + qq) * 1024 + h * 64 + dg * 8) = val;
    }
  }
}

// ---------------- GEMM 2: out = values @ W_out + b (fp32 out) ----------------

__global__ __launch_bounds__(256) void gemm_out(const u16* __restrict__ A,   // Ob [4096][1024]
                                                const u16* __restrict__ Bt,  // WoutT [1024][1024]
                                                const float* __restrict__ bias,
                                                float* __restrict__ out) {
  __shared__ u16 lA[128 * 64];
  __shared__ u16 lB[128 * 64];
  const int tid = threadIdx.x;
  const int wave = tid >> 6, lane = tid & 63, ln = lane & 15, quad = lane >> 4;
  const int n0 = blockIdx.x * 128, m0 = blockIdx.y * 128;
  const int wm = (wave & 1) * 64, wn = (wave >> 1) * 64;
  f32x4 acc[4][4] = {};

  for (int kt = 0; kt < 16; ++kt) {
    const int k0 = kt * 64;
    __syncthreads();
#pragma unroll
    for (int i = 0; i < 4; ++i) {
      int c = wave * 4 + i;
      int rb = c >> 1, kgh = c & 1;
      gload_lds16(A + (size_t)(m0 + rb * 16 + ln) * 1024 + k0 + (kgh * 4 + quad) * 8,
                  lA + rb * 1024 + kgh * 512);
      gload_lds16(Bt + (size_t)(n0 + rb * 16 + ln) * 1024 + k0 + (kgh * 4 + quad) * 8,
                  lB + rb * 1024 + kgh * 512);
    }
    __syncthreads();
#pragma unroll
    for (int ks = 0; ks < 2; ++ks) {
      bf16x8 a[4], b[4];
#pragma unroll
      for (int i = 0; i < 4; ++i) {
        a[i] = load_frag(lA + (wm / 16 + i) * 1024 + (ks * 4 + quad) * 128 + ln * 8);
        b[i] = load_frag(lB + (wn / 16 + i) * 1024 + (ks * 4 + quad) * 128 + ln * 8);
      }
#pragma unroll
      for (int mt = 0; mt < 4; ++mt)
#pragma unroll
        for (int nt = 0; nt < 4; ++nt) acc[mt][nt] = mfma16(a[mt], b[nt], acc[mt][nt]);
    }
  }
#pragma unroll
  for (int mt = 0; mt < 4; ++mt) {
    int row = m0 + wm + mt * 16 + quad * 4;
#pragma unroll
    for (int nt = 0; nt < 4; ++nt) {
      int col = n0 + wn + nt * 16 + ln;
      float bv = bias[col];
#pragma unroll
      for (int r = 0; r < 4; ++r)
        out[(size_t)(row + r) * 1024 + col] = acc[mt][nt][r] + bv;
    }
  }
}

// ---------------- launcher ----------------

extern "C" void kernel_launch(void* const* d_in, const int* in_sizes, int n_in,
                              void* d_out, int out_size, void* d_ws, size_t ws_size,
                              hipStream_t stream) {
  const float* x = (const float*)d_in[0];
  const float* W_qkv = (const float*)d_in[1];
  const float* b_qkv = (const float*)d_in[2];
  const float* W_out = (const float*)d_in[3];
  const float* b_out = (const float*)d_in[4];
  float* out = (float*)d_out;

  char* ws = (char*)d_ws;
  const size_t SZ_XB = (size_t)ROWS * D_MODEL * 2;            // 8 MiB
  const size_t SZ_WQKVT = (size_t)3 * D_MODEL * D_MODEL * 2;  // 6 MiB
  const size_t SZ_WOUTT = (size_t)D_MODEL * D_MODEL * 2;      // 2 MiB
  const size_t SZ_HEADS = (size_t)BATCH * NUM_HEADS * SEQ * HEAD_DIM * 2;  // 8 MiB
  u16* xb = (u16*)(ws);
  u16* WqkvT = (u16*)(ws + SZ_XB);
  u16* WoutT = (u16*)(ws + SZ_XB + SZ_WQKVT);
  u16* Qb = (u16*)(ws + SZ_XB + SZ_WQKVT + SZ_WOUTT);
  u16* Kb = (u16*)(ws + SZ_XB + SZ_WQKVT + SZ_WOUTT + SZ_HEADS);
  u16* Vt = (u16*)(ws + SZ_XB + SZ_WQKVT + SZ_WOUTT + 2 * SZ_HEADS);
  u16* Ob = (u16*)(ws + SZ_XB + SZ_WQKVT + SZ_WOUTT + 3 * SZ_HEADS);

  cvt_x_kernel<<<dim3(ROWS * D_MODEL / 4 / 256), dim3(256), 0, stream>>>(x, xb);
  transpose_cvt<<<dim3(D_MODEL / 32, 3 * D_MODEL / 32), dim3(256), 0, stream>>>(W_qkv, WqkvT,
                                                                                D_MODEL, 3 * D_MODEL);
  transpose_cvt<<<dim3(D_MODEL / 32, D_MODEL / 32), dim3(256), 0, stream>>>(W_out, WoutT,
                                                                            D_MODEL, D_MODEL);
  gemm_qkv<<<dim3(3 * D_MODEL / 128, ROWS / 128), dim3(256), 0, stream>>>(xb, WqkvT, b_qkv,
                                                                          Qb, Kb, Vt);
  attn_kernel<<<dim3(SEQ / 32, BATCH * NUM_HEADS), dim3(128), 0, stream>>>(Qb, Kb, Vt, Ob);
  gemm_out<<<dim3(D_MODEL / 128, ROWS / 128), dim3(256), 0, stream>>>(Ob, WoutT, b_out, out);
}

// Round 6
// 266.759 us; speedup vs baseline: 1.1715x; 1.1715x over previous
//
#include <hip/hip_runtime.h>
#include <hip/hip_bf16.h>

#define D_MODEL 1024
#define NUM_HEADS 16
#define HEAD_DIM 64
#define SEQ 2048
#define BATCH 2
#define ROWS (BATCH * SEQ)  // 4096

typedef unsigned short u16;
typedef __bf16 bf16x8 __attribute__((ext_vector_type(8)));
typedef float f32x4 __attribute__((ext_vector_type(4)));

__device__ inline u16 f2bfu(float f) {
  // RNE float->bf16
  unsigned u = __float_as_uint(f);
  unsigned r = (u + 0x7fffu + ((u >> 16) & 1u)) >> 16;
  return (u16)r;
}

__device__ inline f32x4 mfma16(bf16x8 a, bf16x8 b, f32x4 c) {
  return __builtin_amdgcn_mfma_f32_16x16x32_bf16(a, b, c, 0, 0, 0);
}

__device__ inline bf16x8 load_frag(const u16* p) {
  union { uint4 v; bf16x8 f; } u;
  u.v = *(const uint4*)p;
  return u.f;
}

// async global->LDS, 16B per lane; LDS dest = wave-uniform base + lane*16
__device__ inline void gload_lds16(const u16* g, u16* l) {
  __builtin_amdgcn_global_load_lds((const __attribute__((address_space(1))) void*)g,
                                   (__attribute__((address_space(3))) void*)l, 16, 0, 0);
}

// ---------------- converters ----------------

__global__ __launch_bounds__(256) void cvt_x_kernel(const float* __restrict__ x,
                                                    u16* __restrict__ y) {
  int i = blockIdx.x * 256 + threadIdx.x;  // each handles 4 floats
  float4 v = ((const float4*)x)[i];
  union { u16 s[4]; uint2 v2; } o;
  o.s[0] = f2bfu(v.x); o.s[1] = f2bfu(v.y);
  o.s[2] = f2bfu(v.z); o.s[3] = f2bfu(v.w);
  ((uint2*)y)[i] = o.v2;
}

// W [K][N] fp32 -> Wt [N][K] bf16
__global__ __launch_bounds__(256) void transpose_cvt(const float* __restrict__ W,
                                                     u16* __restrict__ Wt,
                                                     int K, int N) {
  __shared__ float t[32][33];
  int k0 = blockIdx.x * 32, n0 = blockIdx.y * 32;
  int c = threadIdx.x & 31, r8 = threadIdx.x >> 5;
#pragma unroll
  for (int i = 0; i < 4; i++) {
    int r = r8 + i * 8;
    t[r][c] = W[(size_t)(k0 + r) * N + n0 + c];
  }
  __syncthreads();
#pragma unroll
  for (int i = 0; i < 4; i++) {
    int r = r8 + i * 8;
    Wt[(size_t)(n0 + r) * K + k0 + c] = f2bfu(t[c][r]);
  }
}

// ---------------- GEMM 1: qkv = x @ W_qkv + b -> Qb/Kb [bh][s][64], Vt [bh][d][s] ----------------
// 128x128 tile, BK=64, global_load_lds width=16, fragment-ordered LDS.
// LDS layout: 16-row block = 16 rows x 64 k = 1024 u16 (block stride 1024),
// granule kg (8 k) at kg*128, row-in-block at ln*8.

__global__ __launch_bounds__(256) void gemm_qkv(const u16* __restrict__ A,   // xb [4096][1024]
                                                const u16* __restrict__ Bt,  // WqkvT [3072][1024]
                                                const float* __restrict__ bias,
                                                u16* __restrict__ Qb, u16* __restrict__ Kb,
                                                u16* __restrict__ Vt) {
  __shared__ u16 lA[128 * 64];
  __shared__ u16 lB[128 * 64];
  const int tid = threadIdx.x;
  const int wave = tid >> 6, lane = tid & 63, ln = lane & 15, quad = lane >> 4;
  const int n0 = blockIdx.x * 128, m0 = blockIdx.y * 128;
  const int wm = (wave & 1) * 64, wn = (wave >> 1) * 64;
  f32x4 acc[4][4] = {};

  for (int kt = 0; kt < 16; ++kt) {
    const int k0 = kt * 64;
    __syncthreads();
#pragma unroll
    for (int i = 0; i < 4; ++i) {
      int c = wave * 4 + i;  // 16 chunks of 1KB each for A and B
      int rb = c >> 1, kgh = c & 1;
      gload_lds16(A + (size_t)(m0 + rb * 16 + ln) * 1024 + k0 + (kgh * 4 + quad) * 8,
                  lA + rb * 1024 + kgh * 512);
      gload_lds16(Bt + (size_t)(n0 + rb * 16 + ln) * 1024 + k0 + (kgh * 4 + quad) * 8,
                  lB + rb * 1024 + kgh * 512);
    }
    __syncthreads();
#pragma unroll
    for (int ks = 0; ks < 2; ++ks) {
      bf16x8 a[4], b[4];
#pragma unroll
      for (int i = 0; i < 4; ++i) {
        a[i] = load_frag(lA + (wm / 16 + i) * 1024 + (ks * 4 + quad) * 128 + ln * 8);
        b[i] = load_frag(lB + (wn / 16 + i) * 1024 + (ks * 4 + quad) * 128 + ln * 8);
      }
#pragma unroll
      for (int mt = 0; mt < 4; ++mt)
#pragma unroll
        for (int nt = 0; nt < 4; ++nt) acc[mt][nt] = mfma16(a[mt], b[nt], acc[mt][nt]);
    }
  }
#pragma unroll
  for (int mt = 0; mt < 4; ++mt) {
    int row = m0 + wm + mt * 16 + quad * 4;
    int bb = row >> 11, s0 = row & 2047;
#pragma unroll
    for (int nt = 0; nt < 4; ++nt) {
      int col = n0 + wn + nt * 16 + ln;
      float bv = bias[col];
      int h = col / 192, rem = col - h * 192, t3 = rem >> 6, d = rem & 63;
      int bh = bb * NUM_HEADS + h;
      if (t3 == 2) {  // V -> transposed layout [bh][d][s], 4 consecutive s packed
        union { u16 s[4]; uint2 v; } pk;
#pragma unroll
        for (int r = 0; r < 4; ++r) pk.s[r] = f2bfu(acc[mt][nt][r] + bv);
        *(uint2*)(Vt + ((size_t)bh * 64 + d) * SEQ + s0) = pk.v;
      } else {
        u16* dst = (t3 == 0) ? Qb : Kb;
#pragma unroll
        for (int r = 0; r < 4; ++r)
          dst[((size_t)bh * SEQ + s0 + r) * 64 + d] = f2bfu(acc[mt][nt][r] + bv);
      }
    }
  }
}

// ---------------- flash attention, block-cooperative K/V staging ----------------
// Block = 4 waves, 64 q-rows (wave w owns rows q0+w*16 .. +15).
// Per 64-key tile: stage K (8KB) + Vt (8KB) into LDS once via global_load_lds w16,
// then per wave: S^T = K·Q^T (A from lK, B = Q regs), softmax(16 rows),
// P via per-wave swizzled LDS, O^T += V^T·P^T (A from lV). 2 barriers/tile.

__global__ __launch_bounds__(256) void attn_kernel(const u16* __restrict__ Qb,
                                                   const u16* __restrict__ Kb,
                                                   const u16* __restrict__ Vt,
                                                   u16* __restrict__ Ob) {
  __shared__ u16 lK[64 * 64];    // fragment order, 4 blocks of 16 key-rows
  __shared__ u16 lV[64 * 64];    // fragment order, 4 blocks of 16 d-rows
  __shared__ u16 lP[4][2304];    // per-wave P swizzle (loop: first 2048) + epilogue (16x72)
  const int tid = threadIdx.x;
  const int wave = tid >> 6, lane = tid & 63;
  const int ln = lane & 15, quad = lane >> 4;
  const int qt = gridDim.x - 1 - blockIdx.x;  // heavy blocks first
  const int q0 = qt * 64;
  const int bh = blockIdx.y;
  const u16* Qg = Qb + (size_t)bh * SEQ * 64;
  const u16* Kg = Kb + (size_t)bh * SEQ * 64;
  const u16* Vg = Vt + (size_t)bh * 64 * SEQ;
  u16* lPw = lP[wave];

  // Q B-frags, loaded once: qf[ks] = Q[q0+wave*16+ln][ks*32+quad*8 ..+8]
  bf16x8 qf[2];
#pragma unroll
  for (int ks = 0; ks < 2; ++ks)
    qf[ks] = load_frag(Qg + (size_t)(q0 + wave * 16 + ln) * 64 + ks * 32 + quad * 8);

  f32x4 o[4] = {};      // O^T: row d=dt*16+quad*4+r, col q=wave*16+ln
  float m_r = -1e30f;   // exp2 domain
  float l_r = 0.f;
  const int kt_max = qt;

  for (int kt = 0; kt <= kt_max; ++kt) {
    __syncthreads();  // previous tile fully consumed
    // stage K tile + V tile: 16 chunks of 1KB, 4 per wave
#pragma unroll
    for (int i = 0; i < 4; ++i) {
      int c = wave * 4 + i;
      if (c < 8) {
        int rb = c >> 1, kgh = c & 1;
        gload_lds16(Kg + (size_t)(kt * 64 + rb * 16 + ln) * 64 + (kgh * 4 + quad) * 8,
                    lK + rb * 1024 + kgh * 512);
      } else {
        int cc = c - 8, rb = cc >> 1, kgh = cc & 1;
        gload_lds16(Vg + (size_t)(rb * 16 + ln) * SEQ + kt * 64 + (kgh * 4 + quad) * 8,
                    lV + rb * 1024 + kgh * 512);
      }
    }
    __syncthreads();  // staging complete (vmcnt drained by barrier)

    // S^T tile: 64 keys x 16 q (per wave)
    f32x4 sc[4] = {};
#pragma unroll
    for (int mt = 0; mt < 4; ++mt) {
#pragma unroll
      for (int ks = 0; ks < 2; ++ks) {
        bf16x8 kf = load_frag(lK + mt * 1024 + (ks * 4 + quad) * 128 + ln * 8);
        sc[mt] = mfma16(kf, qf[ks], sc[mt]);
      }
    }
    const float SC = 0.18033688011112042f;  // log2(e) / sqrt(64)  (exp2 domain)
    const bool diag = (kt == kt_max);
    const int qq = q0 + wave * 16 + ln;
    // scale + causal mask (only diagonal tile can mask)
#pragma unroll
    for (int mt = 0; mt < 4; ++mt) {
      int key0 = kt * 64 + mt * 16 + quad * 4;
#pragma unroll
      for (int r = 0; r < 4; ++r) {
        float v = sc[mt][r] * SC;
        if (diag && (key0 + r > qq)) v = -1e30f;
        sc[mt][r] = v;
      }
    }
    // online softmax: 16 in-lane values + butterfly over quads (lanes ^16, ^32)
    float mloc = sc[0][0];
#pragma unroll
    for (int mt = 0; mt < 4; ++mt)
#pragma unroll
      for (int r = 0; r < 4; ++r) mloc = fmaxf(mloc, sc[mt][r]);
    mloc = fmaxf(mloc, __shfl_xor(mloc, 16));
    mloc = fmaxf(mloc, __shfl_xor(mloc, 32));
    float mnew = fmaxf(m_r, mloc);
    float alpha = __builtin_amdgcn_exp2f(m_r - mnew);
    float sum = 0.f;
#pragma unroll
    for (int mt = 0; mt < 4; ++mt)
#pragma unroll
      for (int r = 0; r < 4; ++r) {
        float p = __builtin_amdgcn_exp2f(sc[mt][r] - mnew);
        sc[mt][r] = p;
        sum += p;
      }
    sum += __shfl_xor(sum, 16);
    sum += __shfl_xor(sum, 32);
    l_r = l_r * alpha + sum;
    m_r = mnew;
#pragma unroll
    for (int dt = 0; dt < 4; ++dt) o[dt] *= alpha;

    // P -> per-wave LDS, [q][k] with k-granule XOR swizzle, packed b64 writes
#pragma unroll
    for (int mt = 0; mt < 4; ++mt) {
      union { u16 s[4]; uint2 v; } pk;
#pragma unroll
      for (int r = 0; r < 4; ++r) pk.s[r] = f2bfu(sc[mt][r]);
      int addr = ln * 64 + (((mt * 2 + (quad >> 1)) ^ (ln & 7)) * 8) + (quad & 1) * 4;
      *(uint2*)(lPw + addr) = pk.v;
    }
    bf16x8 pf[2];
#pragma unroll
    for (int ks = 0; ks < 2; ++ks)
      pf[ks] = load_frag(lPw + ln * 64 + (((ks * 4 + quad) ^ (ln & 7)) * 8));
    // O^T += V^T · P^T
#pragma unroll
    for (int dt = 0; dt < 4; ++dt) {
#pragma unroll
      for (int ks = 0; ks < 2; ++ks) {
        bf16x8 av = load_frag(lV + dt * 1024 + (ks * 4 + quad) * 128 + ln * 8);
        o[dt] = mfma16(av, pf[ks], o[dt]);
      }
    }
  }

  // epilogue: normalize, transpose O^T -> [q][d] via wave-private LDS, 16B stores
  float inv = 1.f / l_r;
#pragma unroll
  for (int dt = 0; dt < 4; ++dt) {
    union { u16 s[4]; uint2 v; } pk;
#pragma unroll
    for (int r = 0; r < 4; ++r) pk.s[r] = f2bfu(o[dt][r] * inv);
    *(uint2*)(lPw + ln * 72 + dt * 16 + quad * 4) = pk.v;
  }
  const int b = bh >> 4, h = bh & 15;
#pragma unroll
  for (int i = 0; i < 2; ++i) {
    int c = lane + i * 64;
    int qq2 = c >> 3, dg = c & 7;
    uint4 val = *(const uint4*)(lPw + qq2 * 72 + dg * 8);
    *(uint4*)(Ob + ((size_t)b * SEQ + q0 + wave * 16 + qq2) * 1024 + h * 64 + dg * 8) = val;
  }
}

// ---------------- GEMM 2: out = values @ W_out + b (fp32 out) ----------------

__global__ __launch_bounds__(256) void gemm_out(const u16* __restrict__ A,   // Ob [4096][1024]
                                                const u16* __restrict__ Bt,  // WoutT [1024][1024]
                                                const float* __restrict__ bias,
                                                float* __restrict__ out) {
  __shared__ u16 lA[128 * 64];
  __shared__ u16 lB[128 * 64];
  const int tid = threadIdx.x;
  const int wave = tid >> 6, lane = tid & 63, ln = lane & 15, quad = lane >> 4;
  const int n0 = blockIdx.x * 128, m0 = blockIdx.y * 128;
  const int wm = (wave & 1) * 64, wn = (wave >> 1) * 64;
  f32x4 acc[4][4] = {};

  for (int kt = 0; kt < 16; ++kt) {
    const int k0 = kt * 64;
    __syncthreads();
#pragma unroll
    for (int i = 0; i < 4; ++i) {
      int c = wave * 4 + i;
      int rb = c >> 1, kgh = c & 1;
      gload_lds16(A + (size_t)(m0 + rb * 16 + ln) * 1024 + k0 + (kgh * 4 + quad) * 8,
                  lA + rb * 1024 + kgh * 512);
      gload_lds16(Bt + (size_t)(n0 + rb * 16 + ln) * 1024 + k0 + (kgh * 4 + quad) * 8,
                  lB + rb * 1024 + kgh * 512);
    }
    __syncthreads();
#pragma unroll
    for (int ks = 0; ks < 2; ++ks) {
      bf16x8 a[4], b[4];
#pragma unroll
      for (int i = 0; i < 4; ++i) {
        a[i] = load_frag(lA + (wm / 16 + i) * 1024 + (ks * 4 + quad) * 128 + ln * 8);
        b[i] = load_frag(lB + (wn / 16 + i) * 1024 + (ks * 4 + quad) * 128 + ln * 8);
      }
#pragma unroll
      for (int mt = 0; mt < 4; ++mt)
#pragma unroll
        for (int nt = 0; nt < 4; ++nt) acc[mt][nt] = mfma16(a[mt], b[nt], acc[mt][nt]);
    }
  }
#pragma unroll
  for (int mt = 0; mt < 4; ++mt) {
    int row = m0 + wm + mt * 16 + quad * 4;
#pragma unroll
    for (int nt = 0; nt < 4; ++nt) {
      int col = n0 + wn + nt * 16 + ln;
      float bv = bias[col];
#pragma unroll
      for (int r = 0; r < 4; ++r)
        out[(size_t)(row + r) * 1024 + col] = acc[mt][nt][r] + bv;
    }
  }
}

// ---------------- launcher ----------------

extern "C" void kernel_launch(void* const* d_in, const int* in_sizes, int n_in,
                              void* d_out, int out_size, void* d_ws, size_t ws_size,
                              hipStream_t stream) {
  const float* x = (const float*)d_in[0];
  const float* W_qkv = (const float*)d_in[1];
  const float* b_qkv = (const float*)d_in[2];
  const float* W_out = (const float*)d_in[3];
  const float* b_out = (const float*)d_in[4];
  float* out = (float*)d_out;

  char* ws = (char*)d_ws;
  const size_t SZ_XB = (size_t)ROWS * D_MODEL * 2;            // 8 MiB
  const size_t SZ_WQKVT = (size_t)3 * D_MODEL * D_MODEL * 2;  // 6 MiB
  const size_t SZ_WOUTT = (size_t)D_MODEL * D_MODEL * 2;      // 2 MiB
  const size_t SZ_HEADS = (size_t)BATCH * NUM_HEADS * SEQ * HEAD_DIM * 2;  // 8 MiB
  u16* xb = (u16*)(ws);
  u16* WqkvT = (u16*)(ws + SZ_XB);
  u16* WoutT = (u16*)(ws + SZ_XB + SZ_WQKVT);
  u16* Qb = (u16*)(ws + SZ_XB + SZ_WQKVT + SZ_WOUTT);
  u16* Kb = (u16*)(ws + SZ_XB + SZ_WQKVT + SZ_WOUTT + SZ_HEADS);
  u16* Vt = (u16*)(ws + SZ_XB + SZ_WQKVT + SZ_WOUTT + 2 * SZ_HEADS);
  u16* Ob = (u16*)(ws + SZ_XB + SZ_WQKVT + SZ_WOUTT + 3 * SZ_HEADS);

  cvt_x_kernel<<<dim3(ROWS * D_MODEL / 4 / 256), dim3(256), 0, stream>>>(x, xb);
  transpose_cvt<<<dim3(D_MODEL / 32, 3 * D_MODEL / 32), dim3(256), 0, stream>>>(W_qkv, WqkvT,
                                                                                D_MODEL, 3 * D_MODEL);
  transpose_cvt<<<dim3(D_MODEL / 32, D_MODEL / 32), dim3(256), 0, stream>>>(W_out, WoutT,
                                                                            D_MODEL, D_MODEL);
  gemm_qkv<<<dim3(3 * D_MODEL / 128, ROWS / 128), dim3(256), 0, stream>>>(xb, WqkvT, b_qkv,
                                                                          Qb, Kb, Vt);
  attn_kernel<<<dim3(SEQ / 64, BATCH * NUM_HEADS), dim3(256), 0, stream>>>(Qb, Kb, Vt, Ob);
  gemm_out<<<dim3(D_MODEL / 128, ROWS / 128), dim3(256), 0, stream>>>(Ob, WoutT, b_out, out);
}

// Round 7
// 233.764 us; speedup vs baseline: 1.3369x; 1.1411x over previous
//
#include <hip/hip_runtime.h>
#include <hip/hip_bf16.h>

#define D_MODEL 1024
#define NUM_HEADS 16
#define HEAD_DIM 64
#define SEQ 2048
#define BATCH 2
#define ROWS (BATCH * SEQ)  // 4096

typedef unsigned short u16;
typedef __bf16 bf16x8 __attribute__((ext_vector_type(8)));
typedef float f32x4 __attribute__((ext_vector_type(4)));

__device__ inline u16 f2bfu(float f) {
  // RNE float->bf16
  unsigned u = __float_as_uint(f);
  unsigned r = (u + 0x7fffu + ((u >> 16) & 1u)) >> 16;
  return (u16)r;
}

// packed f32x2 -> bf16x2 (one v_cvt_pk_bf16_f32 on gfx950; RNE fallback otherwise)
__device__ inline unsigned cvt_pk_bf16(float a, float b) {
#if __has_builtin(__builtin_amdgcn_cvt_pk_bf16_f32)
  auto r = __builtin_amdgcn_cvt_pk_bf16_f32(a, b);
  unsigned u;
  __builtin_memcpy(&u, &r, 4);
  return u;
#else
  return (unsigned)f2bfu(a) | ((unsigned)f2bfu(b) << 16);
#endif
}

__device__ inline f32x4 mfma16(bf16x8 a, bf16x8 b, f32x4 c) {
  return __builtin_amdgcn_mfma_f32_16x16x32_bf16(a, b, c, 0, 0, 0);
}

__device__ inline bf16x8 load_frag(const u16* p) {
  union { uint4 v; bf16x8 f; } u;
  u.v = *(const uint4*)p;
  return u.f;
}

// async global->LDS, 16B per lane; LDS dest = wave-uniform base + lane*16
__device__ inline void gload_lds16(const u16* g, u16* l) {
  __builtin_amdgcn_global_load_lds((const __attribute__((address_space(1))) void*)g,
                                   (__attribute__((address_space(3))) void*)l, 16, 0, 0);
}

// ---------------- converters ----------------

__global__ __launch_bounds__(256) void cvt_x_kernel(const float* __restrict__ x,
                                                    u16* __restrict__ y) {
  int i = blockIdx.x * 256 + threadIdx.x;  // each handles 4 floats
  float4 v = ((const float4*)x)[i];
  uint2 o;
  o.x = cvt_pk_bf16(v.x, v.y);
  o.y = cvt_pk_bf16(v.z, v.w);
  ((uint2*)y)[i] = o;
}

// W [K][N] fp32 -> Wt [N][K] bf16
__global__ __launch_bounds__(256) void transpose_cvt(const float* __restrict__ W,
                                                     u16* __restrict__ Wt,
                                                     int K, int N) {
  __shared__ float t[32][33];
  int k0 = blockIdx.x * 32, n0 = blockIdx.y * 32;
  int c = threadIdx.x & 31, r8 = threadIdx.x >> 5;
#pragma unroll
  for (int i = 0; i < 4; i++) {
    int r = r8 + i * 8;
    t[r][c] = W[(size_t)(k0 + r) * N + n0 + c];
  }
  __syncthreads();
#pragma unroll
  for (int i = 0; i < 4; i++) {
    int r = r8 + i * 8;
    Wt[(size_t)(n0 + r) * K + k0 + c] = f2bfu(t[c][r]);
  }
}

// ---------------- GEMM 1: qkv = x @ W_qkv + b -> Qb/Kb [bh][s][64], Vt [bh][d][s] ----------------
// 128x128 tile, BK=64, global_load_lds width=16, fragment-ordered LDS.
// LDS layout: 16-row block = 16 rows x 64 k = 1024 u16 (block stride 1024),
// granule kg (8 k) at kg*128, row-in-block at ln*8.

__global__ __launch_bounds__(256) void gemm_qkv(const u16* __restrict__ A,   // xb [4096][1024]
                                                const u16* __restrict__ Bt,  // WqkvT [3072][1024]
                                                const float* __restrict__ bias,
                                                u16* __restrict__ Qb, u16* __restrict__ Kb,
                                                u16* __restrict__ Vt) {
  __shared__ u16 lA[128 * 64];
  __shared__ u16 lB[128 * 64];
  const int tid = threadIdx.x;
  const int wave = tid >> 6, lane = tid & 63, ln = lane & 15, quad = lane >> 4;
  const int n0 = blockIdx.x * 128, m0 = blockIdx.y * 128;
  const int wm = (wave & 1) * 64, wn = (wave >> 1) * 64;
  f32x4 acc[4][4] = {};

  for (int kt = 0; kt < 16; ++kt) {
    const int k0 = kt * 64;
    __syncthreads();
#pragma unroll
    for (int i = 0; i < 4; ++i) {
      int c = wave * 4 + i;  // 16 chunks of 1KB each for A and B
      int rb = c >> 1, kgh = c & 1;
      gload_lds16(A + (size_t)(m0 + rb * 16 + ln) * 1024 + k0 + (kgh * 4 + quad) * 8,
                  lA + rb * 1024 + kgh * 512);
      gload_lds16(Bt + (size_t)(n0 + rb * 16 + ln) * 1024 + k0 + (kgh * 4 + quad) * 8,
                  lB + rb * 1024 + kgh * 512);
    }
    __syncthreads();
#pragma unroll
    for (int ks = 0; ks < 2; ++ks) {
      bf16x8 a[4], b[4];
#pragma unroll
      for (int i = 0; i < 4; ++i) {
        a[i] = load_frag(lA + (wm / 16 + i) * 1024 + (ks * 4 + quad) * 128 + ln * 8);
        b[i] = load_frag(lB + (wn / 16 + i) * 1024 + (ks * 4 + quad) * 128 + ln * 8);
      }
#pragma unroll
      for (int mt = 0; mt < 4; ++mt)
#pragma unroll
        for (int nt = 0; nt < 4; ++nt) acc[mt][nt] = mfma16(a[mt], b[nt], acc[mt][nt]);
    }
  }
#pragma unroll
  for (int mt = 0; mt < 4; ++mt) {
    int row = m0 + wm + mt * 16 + quad * 4;
    int bb = row >> 11, s0 = row & 2047;
#pragma unroll
    for (int nt = 0; nt < 4; ++nt) {
      int col = n0 + wn + nt * 16 + ln;
      float bv = bias[col];
      int h = col / 192, rem = col - h * 192, t3 = rem >> 6, d = rem & 63;
      int bh = bb * NUM_HEADS + h;
      if (t3 == 2) {  // V -> transposed layout [bh][d][s], 4 consecutive s packed
        uint2 pk;
        pk.x = cvt_pk_bf16(acc[mt][nt][0] + bv, acc[mt][nt][1] + bv);
        pk.y = cvt_pk_bf16(acc[mt][nt][2] + bv, acc[mt][nt][3] + bv);
        *(uint2*)(Vt + ((size_t)bh * 64 + d) * SEQ + s0) = pk;
      } else {
        u16* dst = (t3 == 0) ? Qb : Kb;
#pragma unroll
        for (int r = 0; r < 4; ++r)
          dst[((size_t)bh * SEQ + s0 + r) * 64 + d] = f2bfu(acc[mt][nt][r] + bv);
      }
    }
  }
}

// ---------------- flash attention, balanced-pair blocks ----------------
// Block j (0..15) handles q-tiles lo=j and hi=31-j (64 rows each): total work
// (lo+1)+(hi+1) = 33 key-tiles for EVERY block -> perfect balance.
// 8 waves: waves 0-3 own lo rows (wave&3)*16, waves 4-7 own hi rows.
// Per 64-key tile: stage K (8KB) + Vt (8KB) once via global_load_lds w16 (2 chunks/wave),
// lo-waves predicate off for kt > lo. 2 barriers/tile.
// S^T = K·Q^T (A from lK, B = Q regs); softmax raw-domain (scale folded into exp FMA);
// P via per-wave swizzled LDS (packed cvt); O^T += V^T·P^T (A from lV).

__global__ __launch_bounds__(512) void attn_kernel(const u16* __restrict__ Qb,
                                                   const u16* __restrict__ Kb,
                                                   const u16* __restrict__ Vt,
                                                   u16* __restrict__ Ob) {
  __shared__ u16 lK[64 * 64];   // fragment order, 4 blocks of 16 key-rows
  __shared__ u16 lV[64 * 64];   // fragment order, 4 blocks of 16 d-rows
  __shared__ u16 lP[8][2048];   // per-wave P swizzle + epilogue (16x72 fits)
  const int tid = threadIdx.x;
  const int wave = tid >> 6, lane = tid & 63;
  const int ln = lane & 15, quad = lane >> 4;
  const int j = blockIdx.x;         // 0..15
  const int lo = j, hi = 31 - j;
  const int myt = (wave < 4) ? lo : hi;
  const int q0w = myt * 64 + (wave & 3) * 16;  // this wave's 16-row base
  const int ktend = myt;
  const int bh = blockIdx.y;
  const u16* Qg = Qb + (size_t)bh * SEQ * 64;
  const u16* Kg = Kb + (size_t)bh * SEQ * 64;
  const u16* Vg = Vt + (size_t)bh * 64 * SEQ;
  u16* lPw = lP[wave];

  // staging pointers, hoisted: wave w stages chunks c = w*2, w*2+1 (c<8 -> K, else V)
  const u16* sp[2];
  u16* dp[2];
  const int sstride = (wave < 4) ? 64 * 64 : 64;  // K: +64 rows; V: +64 cols
#pragma unroll
  for (int i = 0; i < 2; ++i) {
    int c = wave * 2 + i;
    if (c < 8) {
      int rb = c >> 1, kgh = c & 1;
      sp[i] = Kg + (size_t)(rb * 16 + ln) * 64 + (kgh * 4 + quad) * 8;
      dp[i] = lK + rb * 1024 + kgh * 512;
    } else {
      int cc = c - 8, rb = cc >> 1, kgh = cc & 1;
      sp[i] = Vg + (size_t)(rb * 16 + ln) * SEQ + (kgh * 4 + quad) * 8;
      dp[i] = lV + rb * 1024 + kgh * 512;
    }
  }

  // Q B-frags, loaded once: qf[ks] = Q[q0w+ln][ks*32+quad*8 ..+8]
  bf16x8 qf[2];
#pragma unroll
  for (int ks = 0; ks < 2; ++ks)
    qf[ks] = load_frag(Qg + (size_t)(q0w + ln) * 64 + ks * 32 + quad * 8);

  f32x4 o[4] = {};     // O^T: row d=dt*16+quad*4+r, col q=ln (this wave's 16 q)
  float m_r = -1e30f;  // raw-score domain
  float l_r = 0.f;
  const float SC = 0.18033688011112042f;  // log2(e) / sqrt(64)
  const int qq = q0w + ln;

  for (int kt = 0; kt <= hi; ++kt) {
    __syncthreads();  // previous tile fully consumed
#pragma unroll
    for (int i = 0; i < 2; ++i) gload_lds16(sp[i], dp[i]);
#pragma unroll
    for (int i = 0; i < 2; ++i) sp[i] += sstride;
    __syncthreads();  // staging complete

    if (kt <= ktend) {
      // S^T tile: 64 keys x 16 q
      f32x4 sc[4] = {};
#pragma unroll
      for (int mt = 0; mt < 4; ++mt) {
#pragma unroll
        for (int ks = 0; ks < 2; ++ks) {
          bf16x8 kf = load_frag(lK + mt * 1024 + (ks * 4 + quad) * 128 + ln * 8);
          sc[mt] = mfma16(kf, qf[ks], sc[mt]);
        }
      }
      // causal mask (raw domain), only possible on this wave's diagonal tile
      if (kt == ktend) {
#pragma unroll
        for (int mt = 0; mt < 4; ++mt) {
          int key0 = kt * 64 + mt * 16 + quad * 4;
#pragma unroll
          for (int r = 0; r < 4; ++r)
            if (key0 + r > qq) sc[mt][r] = -1e30f;
        }
      }
      // online softmax: 16 in-lane values + butterfly over quads (lanes ^16, ^32)
      float mloc = sc[0][0];
#pragma unroll
      for (int mt = 0; mt < 4; ++mt)
#pragma unroll
        for (int r = 0; r < 4; ++r) mloc = fmaxf(mloc, sc[mt][r]);
      mloc = fmaxf(mloc, __shfl_xor(mloc, 16));
      mloc = fmaxf(mloc, __shfl_xor(mloc, 32));
      float mnew = fmaxf(m_r, mloc);
      float alpha = __builtin_amdgcn_exp2f((m_r - mnew) * SC);
      float nmsc = -mnew * SC;
      float sum = 0.f;
#pragma unroll
      for (int mt = 0; mt < 4; ++mt)
#pragma unroll
        for (int r = 0; r < 4; ++r) {
          float p = __builtin_amdgcn_exp2f(__builtin_fmaf(sc[mt][r], SC, nmsc));
          sc[mt][r] = p;
          sum += p;
        }
      sum += __shfl_xor(sum, 16);
      sum += __shfl_xor(sum, 32);
      l_r = l_r * alpha + sum;
      m_r = mnew;
#pragma unroll
      for (int dt = 0; dt < 4; ++dt) o[dt] *= alpha;

      // P -> per-wave LDS, [q][k] with k-granule XOR swizzle, packed b64 writes
#pragma unroll
      for (int mt = 0; mt < 4; ++mt) {
        uint2 pk;
        pk.x = cvt_pk_bf16(sc[mt][0], sc[mt][1]);
        pk.y = cvt_pk_bf16(sc[mt][2], sc[mt][3]);
        int addr = ln * 64 + (((mt * 2 + (quad >> 1)) ^ (ln & 7)) * 8) + (quad & 1) * 4;
        *(uint2*)(lPw + addr) = pk;
      }
      bf16x8 pf[2];
#pragma unroll
      for (int ks = 0; ks < 2; ++ks)
        pf[ks] = load_frag(lPw + ln * 64 + (((ks * 4 + quad) ^ (ln & 7)) * 8));
      // O^T += V^T · P^T
#pragma unroll
      for (int dt = 0; dt < 4; ++dt) {
#pragma unroll
        for (int ks = 0; ks < 2; ++ks) {
          bf16x8 av = load_frag(lV + dt * 1024 + (ks * 4 + quad) * 128 + ln * 8);
          o[dt] = mfma16(av, pf[ks], o[dt]);
        }
      }
    }
  }

  // epilogue: normalize, transpose O^T -> [q][d] via wave-private LDS, 16B stores
  float inv = 1.f / l_r;
#pragma unroll
  for (int dt = 0; dt < 4; ++dt) {
    uint2 pk;
    pk.x = cvt_pk_bf16(o[dt][0] * inv, o[dt][1] * inv);
    pk.y = cvt_pk_bf16(o[dt][2] * inv, o[dt][3] * inv);
    *(uint2*)(lPw + ln * 72 + dt * 16 + quad * 4) = pk;
  }
  const int b = bh >> 4, h = bh & 15;
#pragma unroll
  for (int i = 0; i < 2; ++i) {
    int c = lane + i * 64;
    int qq2 = c >> 3, dg = c & 7;
    uint4 val = *(const uint4*)(lPw + qq2 * 72 + dg * 8);
    *(uint4*)(Ob + ((size_t)b * SEQ + q0w + qq2) * 1024 + h * 64 + dg * 8) = val;
  }
}

// ---------------- GEMM 2: out = values @ W_out + b (fp32 out) ----------------
// 128(M) x 64(N) tiles -> 512 blocks (2/CU), BK=64.

__global__ __launch_bounds__(256) void gemm_out(const u16* __restrict__ A,   // Ob [4096][1024]
                                                const u16* __restrict__ Bt,  // WoutT [1024][1024]
                                                const float* __restrict__ bias,
                                                float* __restrict__ out) {
  __shared__ u16 lA[128 * 64];
  __shared__ u16 lB[64 * 64];
  const int tid = threadIdx.x;
  const int wave = tid >> 6, lane = tid & 63, ln = lane & 15, quad = lane >> 4;
  const int n0 = blockIdx.x * 64, m0 = blockIdx.y * 128;
  const int wm = (wave & 1) * 64, wn = (wave >> 1) * 32;
  f32x4 acc[4][2] = {};

  for (int kt = 0; kt < 16; ++kt) {
    const int k0 = kt * 64;
    __syncthreads();
#pragma unroll
    for (int i = 0; i < 6; ++i) {
      int c = wave * 6 + i;  // 24 chunks: 16 A + 8 B
      if (c < 16) {
        int rb = c >> 1, kgh = c & 1;
        gload_lds16(A + (size_t)(m0 + rb * 16 + ln) * 1024 + k0 + (kgh * 4 + quad) * 8,
                    lA + rb * 1024 + kgh * 512);
      } else {
        int cc = c - 16, rb = cc >> 1, kgh = cc & 1;
        gload_lds16(Bt + (size_t)(n0 + rb * 16 + ln) * 1024 + k0 + (kgh * 4 + quad) * 8,
                    lB + rb * 1024 + kgh * 512);
      }
    }
    __syncthreads();
#pragma unroll
    for (int ks = 0; ks < 2; ++ks) {
      bf16x8 a[4], b[2];
#pragma unroll
      for (int i = 0; i < 4; ++i)
        a[i] = load_frag(lA + (wm / 16 + i) * 1024 + (ks * 4 + quad) * 128 + ln * 8);
#pragma unroll
      for (int i = 0; i < 2; ++i)
        b[i] = load_frag(lB + (wn / 16 + i) * 1024 + (ks * 4 + quad) * 128 + ln * 8);
#pragma unroll
      for (int mt = 0; mt < 4; ++mt)
#pragma unroll
        for (int nt = 0; nt < 2; ++nt) acc[mt][nt] = mfma16(a[mt], b[nt], acc[mt][nt]);
    }
  }
#pragma unroll
  for (int mt = 0; mt < 4; ++mt) {
    int row = m0 + wm + mt * 16 + quad * 4;
#pragma unroll
    for (int nt = 0; nt < 2; ++nt) {
      int col = n0 + wn + nt * 16 + ln;
      float bv = bias[col];
#pragma unroll
      for (int r = 0; r < 4; ++r)
        out[(size_t)(row + r) * 1024 + col] = acc[mt][nt][r] + bv;
    }
  }
}

// ---------------- launcher ----------------

extern "C" void kernel_launch(void* const* d_in, const int* in_sizes, int n_in,
                              void* d_out, int out_size, void* d_ws, size_t ws_size,
                              hipStream_t stream) {
  const float* x = (const float*)d_in[0];
  const float* W_qkv = (const float*)d_in[1];
  const float* b_qkv = (const float*)d_in[2];
  const float* W_out = (const float*)d_in[3];
  const float* b_out = (const float*)d_in[4];
  float* out = (float*)d_out;

  char* ws = (char*)d_ws;
  const size_t SZ_XB = (size_t)ROWS * D_MODEL * 2;            // 8 MiB
  const size_t SZ_WQKVT = (size_t)3 * D_MODEL * D_MODEL * 2;  // 6 MiB
  const size_t SZ_WOUTT = (size_t)D_MODEL * D_MODEL * 2;      // 2 MiB
  const size_t SZ_HEADS = (size_t)BATCH * NUM_HEADS * SEQ * HEAD_DIM * 2;  // 8 MiB
  u16* xb = (u16*)(ws);
  u16* WqkvT = (u16*)(ws + SZ_XB);
  u16* WoutT = (u16*)(ws + SZ_XB + SZ_WQKVT);
  u16* Qb = (u16*)(ws + SZ_XB + SZ_WQKVT + SZ_WOUTT);
  u16* Kb = (u16*)(ws + SZ_XB + SZ_WQKVT + SZ_WOUTT + SZ_HEADS);
  u16* Vt = (u16*)(ws + SZ_XB + SZ_WQKVT + SZ_WOUTT + 2 * SZ_HEADS);
  u16* Ob = (u16*)(ws + SZ_XB + SZ_WQKVT + SZ_WOUTT + 3 * SZ_HEADS);

  cvt_x_kernel<<<dim3(ROWS * D_MODEL / 4 / 256), dim3(256), 0, stream>>>(x, xb);
  transpose_cvt<<<dim3(D_MODEL / 32, 3 * D_MODEL / 32), dim3(256), 0, stream>>>(W_qkv, WqkvT,
                                                                                D_MODEL, 3 * D_MODEL);
  transpose_cvt<<<dim3(D_MODEL / 32, D_MODEL / 32), dim3(256), 0, stream>>>(W_out, WoutT,
                                                                            D_MODEL, D_MODEL);
  gemm_qkv<<<dim3(3 * D_MODEL / 128, ROWS / 128), dim3(256), 0, stream>>>(xb, WqkvT, b_qkv,
                                                                          Qb, Kb, Vt);
  attn_kernel<<<dim3(SEQ / 128, BATCH * NUM_HEADS), dim3(512), 0, stream>>>(Qb, Kb, Vt, Ob);
  gemm_out<<<dim3(D_MODEL / 64, ROWS / 128), dim3(256), 0, stream>>>(Ob, WoutT, b_out, out);
}